// Round 1
// baseline (844.649 us; speedup 1.0000x reference)
//
#include <hip/hip_runtime.h>
#include <math.h>

#define V 23
#define HH 256
#define BB 512
#define LL 1024
#define NOUT 46  // 2V

// Multiplicative inverses mod 23, packed 5 bits/entry into two u64 scalars
// (entries 0..11 in T0, 12..22 in T1) so the inverse lookup is pure SALU.
constexpr unsigned long long packInv(int lo) {
    const int inv[23] = {0,1,12,8,6,14,4,10,3,18,7,21,2,16,5,20,13,19,9,17,15,11,22};
    unsigned long long t = 0;
    for (int i = 0; i < 12; ++i) {
        int idx = lo + i;
        if (idx < 23) t |= (unsigned long long)inv[idx] << (5 * i);
    }
    return t;
}
constexpr unsigned long long INV_T0 = packInv(0);
constexpr unsigned long long INV_T1 = packInv(12);

// VALU max-reduce step via DPP (no DS pipe, ~8 cy vs ~120 cy ds_swizzle)
#define DPPMAX(v, ctrl, rmask)                                                  \
    do {                                                                        \
        unsigned _t = (unsigned)__builtin_amdgcn_update_dpp(                    \
            (int)(v), (int)(v), (ctrl), (rmask), 0xF, false);                   \
        (v) = ((v) > _t) ? (v) : _t;                                            \
    } while (0)

__global__ __launch_bounds__(256, 2)
void daf_kernel(const int* __restrict__ xtok,
                const float* __restrict__ W1,
                const float* __restrict__ b1,
                const float* __restrict__ W2,
                const float* __restrict__ b2,
                float* __restrict__ out)
{
    __shared__ float sV[HH];          // relu(h); wave w only touches [64w,64w+64)
    __shared__ float sP[2][4][64];    // partials [parity][wave][lane], dbl-buffered
                                      // R5: transposed from [..][lane][wave] —
                                      // old layout was 8-way bank-conflicted on
                                      // BOTH the b32 write and the b128 read.
                                      // [p][w][l] => consecutive lanes, conflict-free.
    __shared__ int   sTok[LL];
    __shared__ int   sK[LL];          // emitted symbols; flushed to global at end

    const int tid = threadIdx.x;
    const int w   = tid >> 6;
    const int l   = tid & 63;
    const int b   = blockIdx.x;

    for (int i = tid; i < LL; i += 256) sTok[i] = xtok[(size_t)b * LL + i];

    // Lane roles: lanes 0..22 own net[:V] (loc), lanes 32..54 own net[V:] (scale).
    const bool activeA = (l < V);
    const bool activeB = (l >= 32 && l < 32 + V);
    const bool active  = activeA || activeB;
    const int  col     = activeA ? l : (activeB ? (l - 32 + V) : 0);

    // h_pre in double: 1024 sequential adds stay within 1 ulp of exact c@W1+b1.
    double h_pre = (double)b1[tid];

    const float bias = active ? b2[col] : 0.f;

    // R5: W1 column for this thread, all 23 rows, PINNED in VGPRs. W1 is
    // loop-invariant; the old sW1[k*HH+tid] LDS read put ~120 cy of LDS
    // latency at the END of the serial chain every step. A 5-level cndmask
    // select (~30 cy, VALU) replaces it. Same values, same f64 add order.
    float wrow[V];
    #pragma unroll
    for (int j = 0; j < V; ++j) wrow[j] = W1[j * HH + tid];
    #pragma unroll
    for (int j = 0; j < V; ++j) asm volatile("" : "+v"(wrow[j]));

    // W2 chunk: lane holds W2[64w+ii][col], ii=0..63, PINNED in VGPRs.
    // Without the asm barrier the compiler rematerializes these global loads
    // inside the t-loop (R4: VGPR_Count=56 => 64 VMEM loads/lane/step on the
    // critical chain). Per-scalar "+v" makes each value opaque; 128-bit "+v"
    // (float4) is unsupported ("tied indirect register inputs").
    float wreg[64];
    #pragma unroll
    for (int ii = 0; ii < 64; ++ii)
        wreg[ii] = active ? W2[(size_t)(64 * w + ii) * NOUT + col] : 0.f;
    #pragma unroll
    for (int ii = 0; ii < 64; ++ii) asm volatile("" : "+v"(wreg[ii]));

    __syncthreads();

    for (int t = 0; t < LL; ++t) {
        const int tok = sTok[t];   // issued early; latency hidden under matvec

        // publish v = relu(h); consumed only by this wave's own matvec chunk
        float v = fmaxf((float)h_pre, 0.f);
        sV[tid] = v;

        // matvec partial: wave w covers i in [64w,64w+64); LDS broadcast reads
        const float4* pv = (const float4*)(sV + 64 * w);
        float a0 = 0.f, a1 = 0.f, a2 = 0.f, a3 = 0.f;
        #pragma unroll
        for (int q = 0; q < 16; ++q) {
            float4 vv = pv[q];
            a0 = fmaf(vv.x, wreg[4 * q + 0], a0);
            a1 = fmaf(vv.y, wreg[4 * q + 1], a1);
            a2 = fmaf(vv.z, wreg[4 * q + 2], a2);
            a3 = fmaf(vv.w, wreg[4 * q + 3], a3);
        }
        const int p = t & 1;
        sP[p][w][l] = (a0 + a1) + (a2 + a3);   // conflict-free b32 write
        __syncthreads();   // the ONLY barrier per step

        // reduce 4 wave-partials + bias; stride-64 scalar reads pair into
        // ds_read2_b32, conflict-free (2 lanes/bank = free).
        // Sum order (w0+w1)+(w2+w3) matches the old float4 version bit-exactly.
        const float* pp = &sP[p][0][l];
        const float p0 = pp[0], p1 = pp[64], p2 = pp[128], p3 = pp[192];
        float net = bias + ((p0 + p1) + (p2 + p3));
        int ib = __float_as_int(net);
        unsigned monoraw = (ib < 0) ? ~(unsigned)ib : ((unsigned)ib ^ 0x80000000u);
        const unsigned orig = active ? monoraw : 0u;  // lane's OWN key, preserved

        // dual 32-lane-half max-reduce on a separate register (VALU DPP only)
        unsigned red = orig;
        DPPMAX(red, 0xB1,  0xF);  // quad_perm xor1
        DPPMAX(red, 0x4E,  0xF);  // quad_perm xor2
        DPPMAX(red, 0x141, 0xF);  // row_half_mirror (combine 4-groups)
        DPPMAX(red, 0x140, 0xF);  // row_mirror      (combine 8-groups)
        DPPMAX(red, 0x142, 0xA);  // row_bcast15 into rows 1,3 (combine rows)
        const unsigned sA = (unsigned)__builtin_amdgcn_readlane((int)red, 16);
        const unsigned sB = (unsigned)__builtin_amdgcn_readlane((int)red, 48);

        // winner = lowest lane whose ORIGINAL key equals its half's max
        // (lowest lane == lowest index == np first-max tie-break)
        const unsigned cmpv = (l < 32) ? sA : sB;
        const unsigned long long bal = __ballot(orig == cmpv);
        const int loc = __builtin_ctzll(bal & 0xFFFFFFFFull);  // lane == col
        const int sc  = __builtin_ctzll(bal >> 32);

        // inverse mod 23 from packed scalar table (no LDS on the chain)
        const unsigned long long tt = (sc < 12) ? INV_T0 : INV_T1;
        const int sh  = 5 * (sc - ((sc >= 12) ? 12 : 0));
        const int inv = (int)((tt >> sh) & 31);

        int m = tok - loc;
        m += (m >> 31) & V;            // (tok - loc) mod 23
        const int k = (m * inv) % V;   // compiler magic-mul for %23

        // R5: 1-of-23 register select (depth-5 cndmask tree) replaces the
        // k-indexed LDS read. k is wave-uniform; values are per-lane VGPRs.
        {
            const bool kb0 = (k & 1) != 0;
            const bool kb1 = (k & 2) != 0;
            const bool kb2 = (k & 4) != 0;
            const bool kb3 = (k & 8) != 0;
            const bool kb4 = (k & 16) != 0;
            float s0  = kb0 ? wrow[1]  : wrow[0];
            float s1  = kb0 ? wrow[3]  : wrow[2];
            float s2  = kb0 ? wrow[5]  : wrow[4];
            float s3  = kb0 ? wrow[7]  : wrow[6];
            float s4  = kb0 ? wrow[9]  : wrow[8];
            float s5  = kb0 ? wrow[11] : wrow[10];
            float s6  = kb0 ? wrow[13] : wrow[12];
            float s7  = kb0 ? wrow[15] : wrow[14];
            float s8  = kb0 ? wrow[17] : wrow[16];
            float s9  = kb0 ? wrow[19] : wrow[18];
            float s10 = kb0 ? wrow[21] : wrow[20];
            float s11 = wrow[22];                 // k=22 has bit0 == 0
            float u0 = kb1 ? s1  : s0;
            float u1 = kb1 ? s3  : s2;
            float u2 = kb1 ? s5  : s4;
            float u3 = kb1 ? s7  : s6;
            float u4 = kb1 ? s9  : s8;
            float u5 = kb1 ? s11 : s10;
            float q0 = kb2 ? u1 : u0;
            float q1 = kb2 ? u3 : u2;
            float q2 = kb2 ? u5 : u4;
            float r0 = kb3 ? q1 : q0;
            float r1 = q2;                        // k>=16 has bit3 == 0
            float sel = kb4 ? r1 : r0;
            h_pre += (double)sel;
        }

        if (tid == 0) sK[t] = k;
    }

    __syncthreads();
    float* outb = out + (size_t)b * LL * V;
    for (int t = tid; t < LL; t += 256)
        outb[t * V + sK[t]] = 1.0f;
}

extern "C" void kernel_launch(void* const* d_in, const int* in_sizes, int n_in,
                              void* d_out, int out_size, void* d_ws, size_t ws_size,
                              hipStream_t stream) {
    const int*   xtok = (const int*)d_in[0];
    const float* W1   = (const float*)d_in[1];
    const float* b1   = (const float*)d_in[2];
    const float* W2   = (const float*)d_in[3];
    const float* b2   = (const float*)d_in[4];
    float* out = (float*)d_out;

    // d_out poisoned 0xAA pre-launch: zero it, kernel scatters the 1.0s
    hipMemsetAsync(out, 0, (size_t)out_size * sizeof(float), stream);
    daf_kernel<<<BB, 256, 0, stream>>>(xtok, W1, b1, W2, b2, out);
}

// Round 2
// 780.074 us; speedup vs baseline: 1.0828x; 1.0828x over previous
//
#include <hip/hip_runtime.h>
#include <math.h>

#define V 23
#define HH 256
#define BB 512
#define LL 1024
#define NOUT 46  // 2V

// Multiplicative inverses mod 23, packed 5 bits/entry into two u64 scalars
// (entries 0..11 in T0, 12..22 in T1) so the inverse lookup is pure SALU.
constexpr unsigned long long packInv(int lo) {
    const int inv[23] = {0,1,12,8,6,14,4,10,3,18,7,21,2,16,5,20,13,19,9,17,15,11,22};
    unsigned long long t = 0;
    for (int i = 0; i < 12; ++i) {
        int idx = lo + i;
        if (idx < 23) t |= (unsigned long long)inv[idx] << (5 * i);
    }
    return t;
}
constexpr unsigned long long INV_T0 = packInv(0);
constexpr unsigned long long INV_T1 = packInv(12);

// VALU max-reduce step via DPP (no DS pipe, ~8 cy vs ~120 cy ds_swizzle)
#define DPPMAX(v, ctrl, rmask)                                                  \
    do {                                                                        \
        unsigned _t = (unsigned)__builtin_amdgcn_update_dpp(                    \
            (int)(v), (int)(v), (ctrl), (rmask), 0xF, false);                   \
        (v) = ((v) > _t) ? (v) : _t;                                            \
    } while (0)

__global__ __launch_bounds__(256, 2)
void daf_kernel(const int* __restrict__ xtok,
                const float* __restrict__ W1,
                const float* __restrict__ b1,
                const float* __restrict__ W2,
                const float* __restrict__ b2,
                float* __restrict__ out)
{
    __shared__ float sW1[V * HH];     // W1 rows for the h-update (R6: restored;
                                      // DS pipe has slack, VALU does not — the
                                      // R5 cndmask tree regressed 776->844)
    __shared__ float sP[2][4][64];    // partials [parity][wave][lane], dbl-buffered,
                                      // conflict-free both directions (R5)
    __shared__ int   sTok[LL];
    __shared__ int   sK[LL];          // emitted symbols; flushed to global at end

    const int tid = threadIdx.x;
    const int w   = tid >> 6;
    const int l   = tid & 63;
    const int b   = blockIdx.x;

    for (int i = tid; i < V * HH; i += 256) sW1[i] = W1[i];
    for (int i = tid; i < LL; i += 256) sTok[i] = xtok[(size_t)b * LL + i];

    // Lane roles: lanes 0..22 own net[:V] (loc), lanes 32..54 own net[V:] (scale).
    const bool activeA = (l < V);
    const bool activeB = (l >= 32 && l < 32 + V);
    const bool active  = activeA || activeB;
    const int  col     = activeA ? l : (activeB ? (l - 32 + V) : 0);

    // h_pre in double: 1024 sequential adds stay within 1 ulp of exact c@W1+b1.
    double h_pre = (double)b1[tid];

    const float bias = active ? b2[col] : 0.f;

    // W2 chunk: lane holds W2[64w+ii][col], ii=0..63, PINNED in VGPRs.
    // Without the asm barrier the compiler rematerializes these global loads
    // inside the t-loop (R4: VGPR_Count=56 => 64 VMEM loads/lane/step on the
    // critical chain). Per-scalar "+v" makes each value opaque.
    float wreg[64];
    #pragma unroll
    for (int ii = 0; ii < 64; ++ii)
        wreg[ii] = active ? W2[(size_t)(64 * w + ii) * NOUT + col] : 0.f;
    #pragma unroll
    for (int ii = 0; ii < 64; ++ii) asm volatile("" : "+v"(wreg[ii]));

    __syncthreads();

    for (int t = 0; t < LL; ++t) {
        const int tok = sTok[t];   // issued early; latency hidden under matvec

        // v = relu(h). R6: wave w needs exactly the 64 relu(h) values held by
        // its OWN lanes (h[64w..64w+64) == this wave's tids). The old sV LDS
        // round-trip was a wave-internal broadcast costing 16 KB/wave/step of
        // LDS delivery (16 x ds_read_b128 x 64 lanes ~ 1500 cy/CU/step — the
        // real binder; bank-conflict removal in R5 was neutral because
        // conflicts were on the tiny sP traffic, not this). Replace with
        // v_readlane -> SGPR broadcast + v_fmac with SGPR src0: zero LDS
        // traffic, 128 VALU issues/wave/step.
        const float v = fmaxf((float)h_pre, 0.f);
        const int vbits = __float_as_int(v);

        float a0 = 0.f, a1 = 0.f, a2 = 0.f, a3 = 0.f;
        #pragma unroll
        for (int q = 0; q < 16; ++q) {
            const float v0 = __int_as_float(__builtin_amdgcn_readlane(vbits, 4 * q + 0));
            const float v1 = __int_as_float(__builtin_amdgcn_readlane(vbits, 4 * q + 1));
            const float v2 = __int_as_float(__builtin_amdgcn_readlane(vbits, 4 * q + 2));
            const float v3 = __int_as_float(__builtin_amdgcn_readlane(vbits, 4 * q + 3));
            a0 = fmaf(v0, wreg[4 * q + 0], a0);
            a1 = fmaf(v1, wreg[4 * q + 1], a1);
            a2 = fmaf(v2, wreg[4 * q + 2], a2);
            a3 = fmaf(v3, wreg[4 * q + 3], a3);
        }
        const int p = t & 1;
        sP[p][w][l] = (a0 + a1) + (a2 + a3);   // conflict-free b32 write
        __syncthreads();   // the ONLY barrier per step

        // reduce 4 wave-partials + bias; stride-64 scalar reads pair into
        // ds_read2_b32, conflict-free. Sum order (w0+w1)+(w2+w3) preserved.
        const float* pp = &sP[p][0][l];
        const float p0 = pp[0], p1 = pp[64], p2 = pp[128], p3 = pp[192];
        float net = bias + ((p0 + p1) + (p2 + p3));
        int ib = __float_as_int(net);
        unsigned monoraw = (ib < 0) ? ~(unsigned)ib : ((unsigned)ib ^ 0x80000000u);
        const unsigned orig = active ? monoraw : 0u;  // lane's OWN key, preserved

        // dual 32-lane-half max-reduce on a separate register (VALU DPP only)
        unsigned red = orig;
        DPPMAX(red, 0xB1,  0xF);  // quad_perm xor1
        DPPMAX(red, 0x4E,  0xF);  // quad_perm xor2
        DPPMAX(red, 0x141, 0xF);  // row_half_mirror (combine 4-groups)
        DPPMAX(red, 0x140, 0xF);  // row_mirror      (combine 8-groups)
        DPPMAX(red, 0x142, 0xA);  // row_bcast15 into rows 1,3 (combine rows)
        const unsigned sA = (unsigned)__builtin_amdgcn_readlane((int)red, 16);
        const unsigned sB = (unsigned)__builtin_amdgcn_readlane((int)red, 48);

        // winner = lowest lane whose ORIGINAL key equals its half's max
        // (lowest lane == lowest index == np first-max tie-break)
        const unsigned cmpv = (l < 32) ? sA : sB;
        const unsigned long long bal = __ballot(orig == cmpv);
        const int loc = __builtin_ctzll(bal & 0xFFFFFFFFull);  // lane == col
        const int sc  = __builtin_ctzll(bal >> 32);

        // inverse mod 23 from packed scalar table (no LDS on the chain)
        const unsigned long long tt = (sc < 12) ? INV_T0 : INV_T1;
        const int sh  = 5 * (sc - ((sc >= 12) ? 12 : 0));
        const int inv = (int)((tt >> sh) & 31);

        int m = tok - loc;
        m += (m >> 31) & V;            // (tok - loc) mod 23
        const int k = (m * inv) % V;   // compiler magic-mul for %23

        h_pre += (double)sW1[k * HH + tid];   // stride-1, conflict-free; DS has slack
        if (tid == 0) sK[t] = k;
    }

    __syncthreads();
    float* outb = out + (size_t)b * LL * V;
    for (int t = tid; t < LL; t += 256)
        outb[t * V + sK[t]] = 1.0f;
}

extern "C" void kernel_launch(void* const* d_in, const int* in_sizes, int n_in,
                              void* d_out, int out_size, void* d_ws, size_t ws_size,
                              hipStream_t stream) {
    const int*   xtok = (const int*)d_in[0];
    const float* W1   = (const float*)d_in[1];
    const float* b1   = (const float*)d_in[2];
    const float* W2   = (const float*)d_in[3];
    const float* b2   = (const float*)d_in[4];
    float* out = (float*)d_out;

    // d_out poisoned 0xAA pre-launch: zero it, kernel scatters the 1.0s
    hipMemsetAsync(out, 0, (size_t)out_size * sizeof(float), stream);
    daf_kernel<<<BB, 256, 0, stream>>>(xtok, W1, b1, W2, b2, out);
}

// Round 3
// 687.440 us; speedup vs baseline: 1.2287x; 1.1348x over previous
//
#include <hip/hip_runtime.h>
#include <math.h>

#define V 23
#define HH 256
#define BB 512
#define LL 1024
#define NOUT 46  // 2V

typedef float f32x2 __attribute__((ext_vector_type(2)));
typedef float f32x4 __attribute__((ext_vector_type(4)));

// Multiplicative inverses mod 23, packed 5 bits/entry into two u64 scalars
// (entries 0..11 in T0, 12..22 in T1) so the inverse lookup is pure SALU.
constexpr unsigned long long packInv(int lo) {
    const int inv[23] = {0,1,12,8,6,14,4,10,3,18,7,21,2,16,5,20,13,19,9,17,15,11,22};
    unsigned long long t = 0;
    for (int i = 0; i < 12; ++i) {
        int idx = lo + i;
        if (idx < 23) t |= (unsigned long long)inv[idx] << (5 * i);
    }
    return t;
}
constexpr unsigned long long INV_T0 = packInv(0);
constexpr unsigned long long INV_T1 = packInv(12);

// VALU max-reduce step via DPP (no DS pipe, ~8 cy vs ~120 cy ds_swizzle)
#define DPPMAX(v, ctrl, rmask)                                                  \
    do {                                                                        \
        unsigned _t = (unsigned)__builtin_amdgcn_update_dpp(                    \
            (int)(v), (int)(v), (ctrl), (rmask), 0xF, false);                   \
        (v) = ((v) > _t) ? (v) : _t;                                            \
    } while (0)

__global__ __launch_bounds__(256, 2)
void daf_kernel(const int* __restrict__ xtok,
                const float* __restrict__ W1,
                const float* __restrict__ b1,
                const float* __restrict__ W2,
                const float* __restrict__ b2,
                float* __restrict__ out)
{
    __shared__ float sW1[V * HH];     // W1 rows for the h-update
    __shared__ float sV[HH];          // relu(h); wave w only touches [64w,64w+64)
                                      // R7: restored — uniform-address ds_read
                                      // BROADCASTS (16B, not 1KB); R0==R2 perf
                                      // proved the DS pipe was never the binder.
    __shared__ float sP[2][4][64];    // partials [parity][wave][lane], dbl-buffered,
                                      // conflict-free both directions (R5)
    __shared__ int   sTok[LL];
    __shared__ int   sK[LL];          // emitted symbols; flushed to global at end

    const int tid = threadIdx.x;
    const int w   = tid >> 6;
    const int l   = tid & 63;
    const int b   = blockIdx.x;

    for (int i = tid; i < V * HH; i += 256) sW1[i] = W1[i];
    for (int i = tid; i < LL; i += 256) sTok[i] = xtok[(size_t)b * LL + i];

    // Lane roles: lanes 0..22 own net[:V] (loc), lanes 32..54 own net[V:] (scale).
    const bool activeA = (l < V);
    const bool activeB = (l >= 32 && l < 32 + V);
    const bool active  = activeA || activeB;
    const int  col     = activeA ? l : (activeB ? (l - 32 + V) : 0);

    // h_pre in double: 1024 sequential adds stay within 1 ulp of exact c@W1+b1.
    double h_pre = (double)b1[tid];

    const float bias = active ? b2[col] : 0.f;

    // W2 chunk as 32 float2 pairs: lane holds W2[64w+ii][col], PINNED in VGPR
    // pairs so v_pk_fma_f32 (R7) consumes them directly. Kernel is VALU-issue
    // bound (VALUBusy 57->66% as work moved DS->VALU, dur flat): pk_fma halves
    // the matvec FMA issue count, and dropping readlane (R2) removes 64 more.
    f32x2 wreg2[32];
    #pragma unroll
    for (int ii = 0; ii < 32; ++ii) {
        wreg2[ii].x = active ? W2[(size_t)(64 * w + 2 * ii + 0) * NOUT + col] : 0.f;
        wreg2[ii].y = active ? W2[(size_t)(64 * w + 2 * ii + 1) * NOUT + col] : 0.f;
    }
    #pragma unroll
    for (int ii = 0; ii < 32; ++ii) asm volatile("" : "+v"(wreg2[ii]));

    __syncthreads();

    for (int t = 0; t < LL; ++t) {
        const int tok = sTok[t];   // issued early; latency hidden under matvec

        // publish v = relu(h); consumed only by this wave's own matvec chunk
        // (wave-internal: compiler's lgkmcnt wait orders it, no barrier needed)
        float v = fmaxf((float)h_pre, 0.f);
        sV[tid] = v;

        // matvec partial: wave w covers rows [64w,64w+64). Uniform-address
        // b128 reads broadcast (cheap, idle DS pipe); v_pk_fma_f32 does 2
        // MACs/instr: pk(a0+=vx*w0, a1+=vy*w1) is bit-identical to the two
        // scalar fmafs, so the (a0+a1)+(a2+a3) order is preserved exactly.
        const f32x4* pv = (const f32x4*)(sV + 64 * w);
        f32x2 A01 = {0.f, 0.f};
        f32x2 A23 = {0.f, 0.f};
        #pragma unroll
        for (int q = 0; q < 16; ++q) {
            f32x4 vv = pv[q];
            f32x2 vlo; vlo.x = vv.x; vlo.y = vv.y;
            f32x2 vhi; vhi.x = vv.z; vhi.y = vv.w;
            asm("v_pk_fma_f32 %0, %1, %2, %0" : "+v"(A01) : "v"(vlo), "v"(wreg2[2 * q + 0]));
            asm("v_pk_fma_f32 %0, %1, %2, %0" : "+v"(A23) : "v"(vhi), "v"(wreg2[2 * q + 1]));
        }
        const int p = t & 1;
        sP[p][w][l] = (A01.x + A01.y) + (A23.x + A23.y);   // conflict-free b32 write
        __syncthreads();   // the ONLY barrier per step

        // reduce 4 wave-partials + bias; stride-64 scalar reads pair into
        // ds_read2_b32, conflict-free. Sum order (s0+s1)+(s2+s3) preserved.
        const float* pp = &sP[p][0][l];
        const float p0 = pp[0], p1 = pp[64], p2 = pp[128], p3 = pp[192];
        float net = bias + ((p0 + p1) + (p2 + p3));
        int ib = __float_as_int(net);
        unsigned monoraw = (ib < 0) ? ~(unsigned)ib : ((unsigned)ib ^ 0x80000000u);
        const unsigned orig = active ? monoraw : 0u;  // lane's OWN key, preserved

        // dual 32-lane-half max-reduce on a separate register (VALU DPP only)
        unsigned red = orig;
        DPPMAX(red, 0xB1,  0xF);  // quad_perm xor1
        DPPMAX(red, 0x4E,  0xF);  // quad_perm xor2
        DPPMAX(red, 0x141, 0xF);  // row_half_mirror (combine 4-groups)
        DPPMAX(red, 0x140, 0xF);  // row_mirror      (combine 8-groups)
        DPPMAX(red, 0x142, 0xA);  // row_bcast15 into rows 1,3 (combine rows)
        const unsigned sA = (unsigned)__builtin_amdgcn_readlane((int)red, 16);
        const unsigned sB = (unsigned)__builtin_amdgcn_readlane((int)red, 48);

        // winner = lowest lane whose ORIGINAL key equals its half's max
        // (lowest lane == lowest index == np first-max tie-break)
        const unsigned cmpv = (l < 32) ? sA : sB;
        const unsigned long long bal = __ballot(orig == cmpv);
        const int loc = __builtin_ctzll(bal & 0xFFFFFFFFull);  // lane == col
        const int sc  = __builtin_ctzll(bal >> 32);

        // inverse mod 23 from packed scalar table (no LDS on the chain)
        const unsigned long long tt = (sc < 12) ? INV_T0 : INV_T1;
        const int sh  = 5 * (sc - ((sc >= 12) ? 12 : 0));
        const int inv = (int)((tt >> sh) & 31);

        int m = tok - loc;
        m += (m >> 31) & V;            // (tok - loc) mod 23
        const int k = (m * inv) % V;   // compiler magic-mul for %23

        h_pre += (double)sW1[k * HH + tid];   // stride-1, conflict-free; DS has slack
        if (tid == 0) sK[t] = k;
    }

    __syncthreads();
    float* outb = out + (size_t)b * LL * V;
    for (int t = tid; t < LL; t += 256)
        outb[t * V + sK[t]] = 1.0f;
}

extern "C" void kernel_launch(void* const* d_in, const int* in_sizes, int n_in,
                              void* d_out, int out_size, void* d_ws, size_t ws_size,
                              hipStream_t stream) {
    const int*   xtok = (const int*)d_in[0];
    const float* W1   = (const float*)d_in[1];
    const float* b1   = (const float*)d_in[2];
    const float* W2   = (const float*)d_in[3];
    const float* b2   = (const float*)d_in[4];
    float* out = (float*)d_out;

    // d_out poisoned 0xAA pre-launch: zero it, kernel scatters the 1.0s
    hipMemsetAsync(out, 0, (size_t)out_size * sizeof(float), stream);
    daf_kernel<<<BB, 256, 0, stream>>>(xtok, W1, b1, W2, b2, out);
}